// Round 9
// baseline (284.801 us; speedup 1.0000x reference)
//
#include <hip/hip_runtime.h>

// KrausRK4 via bf16 MFMA, r9: frag-major LDS. All intermediates stored as
// MFMA-operand fragments of hat(X) (slot[rb][s][lane], 16B each, 8KB/matrix).
// assemble(plain C-tile) -> hat frags directly; stores are 2 x 16B vector
// writes; reads are contiguous ds_read_b128. sandHat eliminated: every
// sandwich computed once in plain form. 9 barrier phases, 40KB LDS, 4 blk/CU.

typedef __attribute__((ext_vector_type(16))) float f32x16;
typedef __attribute__((ext_vector_type(8))) __bf16 bf16x8;

#define MATB 8192

__device__ __forceinline__ unsigned short bf16rne(float x) {
  unsigned u = __builtin_bit_cast(unsigned, x);
  return (unsigned short)((u + 0x7FFFu + ((u >> 16) & 1u)) >> 16);
}
__device__ __forceinline__ float bflo(unsigned u) {
  return __builtin_bit_cast(float, u << 16);
}
__device__ __forceinline__ float bfhi(unsigned u) {
  return __builtin_bit_cast(float, u & 0xFFFF0000u);
}
// pack two floats -> 2 bf16 (RNE); plain casts so compiler can fuse to
// v_cvt_pk_bf16_f32 (T12: don't hand-write the asm)
__device__ __forceinline__ unsigned pk2(float lo, float hi) {
  union { __bf16 h[2]; unsigned u; } r;
  r.h[0] = (__bf16)lo;
  r.h[1] = (__bf16)hi;
  return r.u;
}

union U4 { uint4 u; bf16x8 h; };

// Build step-s operand fragment (k = s*16 + lh*8 + i) from a C-tile.
// lower lanes: elems0-3 = own t[b8+0..3], elems4-7 = partner t[b8+0..3]
// upper lanes: elems0-3 = partner t[b8+4..7], elems4-7 = own t[b8+4..7]
// partner = lane ^ 32. 2-shfl version: send the word the partner needs.
__device__ __forceinline__ bf16x8 assemble(const f32x16& t, int b8, int lh) {
  unsigned u0 = pk2(t[b8 + 0], t[b8 + 1]);
  unsigned u1 = pk2(t[b8 + 2], t[b8 + 3]);
  unsigned w0 = pk2(t[b8 + 4], t[b8 + 5]);
  unsigned w1 = pk2(t[b8 + 6], t[b8 + 7]);
  unsigned z0 = lh ? u0 : w0;           // what my partner needs
  unsigned z1 = lh ? u1 : w1;
  unsigned r0 = __shfl_xor(z0, 32);
  unsigned r1 = __shfl_xor(z1, 32);
  U4 r;
  r.u = make_uint4(lh ? r0 : u0, lh ? r1 : u1,
                   lh ? w0 : r0, lh ? w1 : r1);
  return r.h;
}

// ---------------- Um1 = U1 @ inv(Um), fp32 Gauss-Jordan, no pivot -----------
__global__ __launch_bounds__(256) void kraus_invert(
    const float* __restrict__ U1, const float* __restrict__ Um,
    float* __restrict__ Um1) {
  __shared__ float M[64][66];
  __shared__ float X[64][66];
  int tid = threadIdx.x;
#pragma unroll
  for (int it = 0; it < 16; ++it) {
    int idx = tid + 256 * it;
    int r = idx >> 6, c = idx & 63;
    M[r][c] = Um[idx];
    X[r][c] = (r == c) ? 1.0f : 0.0f;
  }
  __syncthreads();
  for (int k = 0; k < 64; ++k) {
    if (tid < 64) {
      float ip = 1.0f / M[k][k];
      M[k][tid] *= ip;
      X[k][tid] *= ip;
    }
    __syncthreads();
    int r = tid & 63, q = tid >> 6;
    float f = M[r][k];
    __syncthreads();
    if (r != k) {
#pragma unroll
      for (int cc = 0; cc < 16; ++cc) {
        int c = q * 16 + cc;
        M[r][c] -= f * M[k][c];
        X[r][c] -= f * X[k][c];
      }
    }
    __syncthreads();
  }
  for (int it = 0; it < 16; ++it) {
    int idx = tid + 256 * it;
    int i = idx >> 6, j = idx & 63;
    float s = 0.0f;
#pragma unroll 4
    for (int k = 0; k < 64; ++k) s += U1[i * 64 + k] * X[k][j];
    Um1[idx] = s;
  }
}

// ---------------- prepack: 15 operators -> bf16 fragment-major in ws --------
// op order: 0=U1 1=Um 2=Um1 3..6=Ls0 7..10=Lsmid 11..14=Ls1
__global__ __launch_bounds__(256) void kraus_prepack(
    const float* __restrict__ U1, const float* __restrict__ Um,
    const float* __restrict__ Ls0, const float* __restrict__ Lsmid,
    const float* __restrict__ Ls1, float* __restrict__ ws) {
  const float* Um1 = ws;
  unsigned short* dst = (unsigned short*)((char*)ws + 16384);
  int o = blockIdx.x;
  const float* s;
  if (o == 0) s = U1;
  else if (o == 1) s = Um;
  else if (o == 2) s = Um1;
  else if (o < 7) s = Ls0 + (o - 3) * 4096;
  else if (o < 11) s = Lsmid + (o - 7) * 4096;
  else s = Ls1 + (o - 11) * 4096;
  unsigned short* d = dst + o * 4096;
  int tid = threadIdx.x;
#pragma unroll
  for (int j = 0; j < 16; ++j) {
    int idx = tid + 256 * j;
    int f = idx >> 9, l = (idx >> 3) & 63, i = idx & 7;
    int t = f >> 2, ss = f & 3;
    int R = t * 32 + (l & 31);
    int C = ss * 16 + (l >> 5) * 8 + i;
    d[idx] = bf16rne(s[R * 64 + C]);
  }
}

// ---------------- main kernel: one block per batch item, 9 phases -----------
__global__ __launch_bounds__(256, 4) void kraus_main(
    const float* __restrict__ rho0g, const float* __restrict__ dtp,
    const char* __restrict__ gfrag, float* __restrict__ outg) {
  __shared__ __align__(16) char lds[5 * MATB];   // 40960 B -> 4 blocks/CU
  char* S0 = lds;              // rho0 frags
  char* S1 = S0 + MATB;        // J0 -> P -> rho4
  char* S2 = S1 + MATB;        // T -> J2
  char* S3 = S2 + MATB;        // rho2 -> rho3
  char* S4 = S3 + MATB;        // S -> J3

  const int tid = threadIdx.x;
  const int l = tid & 63, w = tid >> 6;
  const int ti = w >> 1, tj = w & 1;
  const int l31 = l & 31, lh = l >> 5;
  const int fragoff = l * 16;
  const int myslot = ((tj * 4 + 2 * ti) << 10) + fragoff;  // sigma=0; +1024 for 1
  const float dt = dtp[0];
  const size_t b = blockIdx.x;

  auto GF = [&](int op, int blk) {
    return gfrag + op * 8192 + blk * 4096 + l * 16;
  };
  // acc += (frag-major hat X) @ opfrag^T for row-block a:  -> T^T C-tile
  auto mmA = [&](f32x16& acc, const char* X, int a, const char* __restrict__ gQ) {
#pragma unroll
    for (int s = 0; s < 4; ++s) {
      bf16x8 aa = *(const bf16x8*)(X + ((a * 4 + s) << 10) + fragoff);
      bf16x8 bb = *(const bf16x8*)(gQ + s * 1024);
      acc = __builtin_amdgcn_mfma_f32_32x32x16_bf16(aa, bb, acc, 0, 0, 0);
    }
  };
  // acc += plain (op1 @ X @ op2^T)[ti][tj]  (X = frag-major hat in LDS)
  auto sandP = [&](f32x16& acc, const char* X, int op1, int op2) {
    f32x16 t0 = {}, t1 = {};
    mmA(t0, X, 0, GF(op1, ti));
    mmA(t1, X, 1, GF(op1, ti));
    const char* gQ = GF(op2, tj);
#pragma unroll
    for (int s = 0; s < 4; ++s) {
      bf16x8 p = assemble((s < 2) ? t0 : t1, (s & 1) * 8, lh);
      bf16x8 q = *(const bf16x8*)(gQ + s * 1024);
      acc = __builtin_amdgcn_mfma_f32_32x32x16_bf16(p, q, acc, 0, 0, 0);
    }
  };
  // store hat-frags of plain C-tile into frag-major matrix dst
  auto storeF = [&](char* dst, const f32x16& acc) {
#pragma unroll
    for (int sg = 0; sg < 2; ++sg) {
      bf16x8 f = assemble(acc, sg * 8, lh);
      *(bf16x8*)(dst + myslot + (sg << 10)) = f;
    }
  };
  // D = A + s*B on raw dwords (frag-major, elementwise-safe)
  auto axpy = [&](char* D, const char* A, float s, const char* Bm) {
#pragma unroll
    for (int j = 0; j < 8; ++j) {
      int off = (tid + 256 * j) * 4;
      unsigned a = *(const unsigned*)(A + off);
      unsigned bb = *(const unsigned*)(Bm + off);
      *(unsigned*)(D + off) = pk2(bflo(a) + s * bflo(bb), bfhi(a) + s * bfhi(bb));
    }
  };

  // ph1: stage rho0 -> hat frags in S0
  // elem (row r, col c) -> slot[c>>5][r>>4], lane (c&31)+32*((r>>3)&1), i=r&7
  {
    const float* src = rho0g + b * 4096 + tid * 16;
    float vals[16];
#pragma unroll
    for (int q = 0; q < 4; ++q) {
      float4 f = *(const float4*)(src + q * 4);
      vals[q * 4 + 0] = f.x; vals[q * 4 + 1] = f.y;
      vals[q * 4 + 2] = f.z; vals[q * 4 + 3] = f.w;
    }
    int r = tid >> 2, c0 = (tid & 3) * 16;
    int base = ((r >> 4) << 10) + ((r & 7) * 2) + (((r >> 3) & 1) * 32) * 16;
#pragma unroll
    for (int u = 0; u < 16; ++u) {
      int c = c0 + u;
      *(unsigned short*)(S0 + ((c >> 5) << 12) + base + (c & 31) * 16) =
          bf16rne(vals[u]);
    }
  }
  __syncthreads();

  f32x16 outacc = {};

  // ph2: J0 = sum_k plain(L0k rho0 L0k^T) [reads S0] -> frags S1
  {
    f32x16 J = {};
#pragma unroll
    for (int k = 0; k < 4; ++k) sandP(J, S0, 3 + k, 3 + k);
    storeF(S1, J);
  }
  __syncthreads();

  // ph3: out += dt/6 * plain(U1,J0) [S1]; That = rho0 + 0.5dt*J0 -> S2
  {
    f32x16 a = {};
    sandP(a, S1, 0, 0);
    outacc += (dt / 6.f) * a;
    axpy(S2, S0, 0.5f * dt, S1);
  }
  __syncthreads();

  // ph4: A=plain(U1,rho0): out+=A, P frags->S1 (J0 dead);
  //      rho2 = plain(Um,T) -> S3; S = plain(Um,rho0) -> S4
  {
    { f32x16 A = {}; sandP(A, S0, 0, 0); outacc += A; storeF(S1, A); }
    { f32x16 r2 = {}; sandP(r2, S2, 1, 1); storeF(S3, r2); }
    { f32x16 Sh = {}; sandP(Sh, S0, 1, 1); storeF(S4, Sh); }
  }
  __syncthreads();

  // ph5: J2 [reads S3=rho2] -> S2 (T dead)
  {
    f32x16 J = {};
#pragma unroll
    for (int k = 0; k < 4; ++k) sandP(J, S3, 7 + k, 7 + k);
    storeF(S2, J);
  }
  __syncthreads();

  // ph6: rho3 = S + 0.5dt*J2 -> S3 (rho2 dead)
  axpy(S3, S4, 0.5f * dt, S2);
  __syncthreads();

  // ph7: J3 [reads S3] -> S4 (S dead)
  {
    f32x16 J = {};
#pragma unroll
    for (int k = 0; k < 4; ++k) sandP(J, S3, 7 + k, 7 + k);
    storeF(S4, J);
  }
  __syncthreads();

  // ph8: out += dt/3*(plain(Um1,J2)[S2] + plain(Um1,J3)[S4]);
  //      rho4 frags = P frags + dt*hat(plain(Um1,J3)) (rmw own S1 slots)
  {
    { f32x16 a = {}; sandP(a, S2, 2, 2); outacc += (dt / 3.f) * a; }
    {
      f32x16 g = {};
      sandP(g, S4, 2, 2);
      outacc += (dt / 3.f) * g;
#pragma unroll
      for (int sg = 0; sg < 2; ++sg) {
        bf16x8 F = assemble(g, sg * 8, lh);
        char* p = S1 + myslot + (sg << 10);
        bf16x8 old = *(const bf16x8*)p;
        bf16x8 nw;
#pragma unroll
        for (int i = 0; i < 8; ++i)
          nw[i] = (__bf16)((float)old[i] + dt * (float)F[i]);
        *(bf16x8*)p = nw;
      }
    }
  }
  __syncthreads();

  // ph9: out += dt/6 * jump(Ls1, rho4) [reads S1]
  {
    f32x16 J = {};
#pragma unroll
    for (int k = 0; k < 4; ++k) sandP(J, S1, 11 + k, 11 + k);
    outacc += (dt / 6.f) * J;
  }

  // store fp32 output tile (plain C layout)
  {
    float* op = outg + b * 4096 + (size_t)(ti * 32 + lh * 4) * 64 + tj * 32 + l31;
#pragma unroll
    for (int r = 0; r < 16; ++r) {
      int row = (r & 3) + 8 * (r >> 2);
      op[row * 64] = outacc[r];
    }
  }
}

extern "C" void kernel_launch(void* const* d_in, const int* in_sizes, int n_in,
                              void* d_out, int out_size, void* d_ws, size_t ws_size,
                              hipStream_t stream) {
  const float* rho0 = (const float*)d_in[0];
  const float* U1 = (const float*)d_in[1];
  const float* Um = (const float*)d_in[2];
  const float* Ls0 = (const float*)d_in[3];
  const float* Lsmid = (const float*)d_in[4];
  const float* Ls1 = (const float*)d_in[5];
  const float* dtp = (const float*)d_in[6];
  float* out = (float*)d_out;
  float* ws = (float*)d_ws;   // [0,16KB): Um1 fp32; [16KB,136KB): bf16 frags

  const int B = in_sizes[0] >> 12;

  kraus_invert<<<1, 256, 0, stream>>>(U1, Um, ws);
  kraus_prepack<<<15, 256, 0, stream>>>(U1, Um, Ls0, Lsmid, Ls1, ws);
  kraus_main<<<B, 256, 0, stream>>>(rho0, dtp, (const char*)d_ws + 16384, out);
}